// Round 6
// baseline (111.685 us; speedup 1.0000x reference)
//
#include <hip/hip_runtime.h>

#define DIM 512

typedef unsigned int uint;
typedef unsigned short ushort;
typedef __attribute__((ext_vector_type(8))) short short8;
typedef __attribute__((ext_vector_type(4))) float f32x4;

// Pack two fp32 -> two bf16 (RNE-ish via +0x8000), lo16 = first arg.
__device__ __forceinline__ uint pack_bf16(float a, float b) {
    union { float f; uint u; } ua, ub;
    ua.f = a; ub.f = b;
    uint x0 = ua.u + 0x8000u;
    uint x1 = ub.u + 0x8000u;
    return __builtin_amdgcn_perm(x1, x0, 0x07060302);
}

// (bf16 pair u) * (x_even, x_odd) -> bf16 pair. lo16 of u = even element.
__device__ __forceinline__ uint mul_pack(uint u, float xl, float xh) {
    union { float f; uint u; } lo, hi, a, b;
    lo.u = u << 16;            // fp32 of even bf16
    hi.u = u & 0xffff0000u;    // fp32 of odd bf16
    a.f = lo.f * xl;
    b.f = hi.f * xh;
    return __builtin_amdgcn_perm(b.u + 0x8000u, a.u + 0x8000u, 0x07060302);
}

// =====================================================================
// K1: convert y and z (256x512 fp32) to bf16 in MFMA-fragment-swizzled
// order: elem (row,k) -> dst[ (g*16+kt)*512 + lane*8 + j ] where
// g=row>>4, kt=k>>5, lane=((k>>3)&3)*16 + (row&15), j=k&7.
// A wave's frag load for (g,kt) is then ONE contiguous 1KB dwordx4 load.
// Writes fully coalesced (thread t writes 16B at t*16).
// =====================================================================
__global__ void conv_swizzle(const float* __restrict__ z, const float* __restrict__ y,
                             ushort* __restrict__ zbf, ushort* __restrict__ ybf) {
    int t = blockIdx.x * 256 + threadIdx.x;      // 0..32767
    int idx = t & 16383;
    const float* src = (t < 16384) ? z : y;
    ushort* dst = (t < 16384) ? zbf : ybf;
    int r15  = idx & 15;
    int quad = (idx >> 4) & 3;
    int kt   = (idx >> 6) & 15;
    int g    = idx >> 10;
    const float* p = src + (g * 16 + r15) * DIM + kt * 32 + quad * 8;
    float4 a = *(const float4*)(p);
    float4 b = *(const float4*)(p + 4);
    uint4 o;
    o.x = pack_bf16(a.x, a.y);
    o.y = pack_bf16(a.z, a.w);
    o.z = pack_bf16(b.x, b.y);
    o.w = pack_bf16(b.z, b.w);
    *(uint4*)(dst + idx * 8) = o;
}

// =====================================================================
// K2: fused diag + batched GEMM + LSE partials. NO LDS, NO BARRIERS in
// the K-loop: fragments load straight from L2-resident swizzled ybf/zbf
// with coalesced 1KB dwordx4 loads; A = x (.) y formed in-register.
// block = (a, rt): T[a, rt*128:(rt+1)*128, 0:256]; 8 waves, 64x64 each.
// =====================================================================
__global__ void __launch_bounds__(512, 4)
gemm_fused(const float* __restrict__ x, const float* __restrict__ y,
           const float* __restrict__ z,
           const ushort* __restrict__ ybf, const ushort* __restrict__ zbf,
           float* __restrict__ rowM, float* __restrict__ rowS,
           float* __restrict__ colM, float* __restrict__ colS,
           float* __restrict__ diag, uint* __restrict__ counter) {
    __shared__ float redA[128 * 4];
    __shared__ float rowMaxS[128];
    __shared__ float redB[256 * 2];
    __shared__ float colMaxS[256];
    __shared__ float dred[8];

    const int tid = threadIdx.x;
    const int a   = blockIdx.x >> 1;
    const int rt  = blockIdx.x & 1;

    if (blockIdx.x == 0 && tid == 0) *counter = 0u;   // reset K3's flag each call

    const int lane = tid & 63;
    const int wave = tid >> 6;
    const int quad = lane >> 4;
    const int ln15 = lane & 15;
    const int wr = wave >> 2;     // 0..1
    const int wc = wave & 3;      // 0..3

    // ---- fused diag: T[a,a,a] exact fp32 (rt==0 blocks only) ----
    if (rt == 0) {
        float p = x[a * DIM + tid] * y[a * DIM + tid] * z[a * DIM + tid];
        #pragma unroll
        for (int m = 1; m < 64; m <<= 1) p += __shfl_xor(p, m, 64);
        if (lane == 0) dred[wave] = p;
    }
    __syncthreads();
    if (rt == 0 && tid == 0) {
        float s = 0.f;
        #pragma unroll
        for (int w2 = 0; w2 < 8; ++w2) s += dred[w2];
        diag[a] = s;
    }

    f32x4 acc[4][4];
    #pragma unroll
    for (int i = 0; i < 4; ++i)
        #pragma unroll
        for (int j = 0; j < 4; ++j)
            acc[i][j] = (f32x4){0.f, 0.f, 0.f, 0.f};

    // fragment bases (halves): frag group g stores 16 kt-chunks of 512 halves
    const ushort* ybase = ybf + (rt * 8 + wr * 4) * 8192 + lane * 8;  // + i*8192 + kt*512
    const ushort* zbase = zbf + (wc * 4) * 8192 + lane * 8;           // + j*8192 + kt*512
    const float*  xrow  = x + a * DIM + quad * 8;                     // + kt*32

    #pragma unroll 2
    for (int kt = 0; kt < 16; ++kt) {
        uint4 zu[4], yu[4];
        #pragma unroll
        for (int j = 0; j < 4; ++j)
            zu[j] = *(const uint4*)(zbase + j * 8192 + kt * 512);
        #pragma unroll
        for (int i = 0; i < 4; ++i)
            yu[i] = *(const uint4*)(ybase + i * 8192 + kt * 512);
        float4 x0 = *(const float4*)(xrow + kt * 32);
        float4 x1 = *(const float4*)(xrow + kt * 32 + 4);

        short8 af[4], bfr[4];
        #pragma unroll
        for (int j = 0; j < 4; ++j)
            bfr[j] = *(short8*)&zu[j];
        #pragma unroll
        for (int i = 0; i < 4; ++i) {
            uint4 o;
            o.x = mul_pack(yu[i].x, x0.x, x0.y);
            o.y = mul_pack(yu[i].y, x0.z, x0.w);
            o.z = mul_pack(yu[i].z, x1.x, x1.y);
            o.w = mul_pack(yu[i].w, x1.z, x1.w);
            af[i] = *(short8*)&o;
        }
        #pragma unroll
        for (int i = 0; i < 4; ++i)
            #pragma unroll
            for (int j = 0; j < 4; ++j)
                acc[i][j] = __builtin_amdgcn_mfma_f32_16x16x32_bf16(af[i], bfr[j], acc[i][j], 0, 0, 0);
    }
    __syncthreads();

    // ===== row-wise LSE partials (reduce over all 256 cols s) =====
    // lane owns rows r = wr*64 + i*16 + quad*4 + reg, cols n = wc*64 + j*16 + ln15
    #pragma unroll
    for (int i = 0; i < 4; ++i) {
        #pragma unroll
        for (int reg = 0; reg < 4; ++reg) {
            float m = fmaxf(fmaxf(acc[i][0][reg], acc[i][1][reg]),
                            fmaxf(acc[i][2][reg], acc[i][3][reg]));
            #pragma unroll
            for (int d = 1; d < 16; d <<= 1) m = fmaxf(m, __shfl_xor(m, d, 64));
            if (ln15 == 0) redA[(wr * 64 + i * 16 + quad * 4 + reg) * 4 + wc] = m;
        }
    }
    __syncthreads();
    if (tid < 128) {
        float m = fmaxf(fmaxf(redA[tid * 4 + 0], redA[tid * 4 + 1]),
                        fmaxf(redA[tid * 4 + 2], redA[tid * 4 + 3]));
        rowMaxS[tid] = m;
    }
    __syncthreads();
    #pragma unroll
    for (int i = 0; i < 4; ++i) {
        #pragma unroll
        for (int reg = 0; reg < 4; ++reg) {
            int r = wr * 64 + i * 16 + quad * 4 + reg;
            float rm = rowMaxS[r];
            float s = __expf(acc[i][0][reg] - rm) + __expf(acc[i][1][reg] - rm)
                    + __expf(acc[i][2][reg] - rm) + __expf(acc[i][3][reg] - rm);
            #pragma unroll
            for (int d = 1; d < 16; d <<= 1) s += __shfl_xor(s, d, 64);
            if (ln15 == 0) redA[r * 4 + wc] = s;
        }
    }
    __syncthreads();
    if (tid < 128) {
        float s = redA[tid * 4 + 0] + redA[tid * 4 + 1] + redA[tid * 4 + 2] + redA[tid * 4 + 3];
        int rg = rt * 128 + tid;
        rowM[a * 256 + rg] = rowMaxS[tid];
        rowS[a * 256 + rg] = s;
    }

    // ===== col-wise LSE partials (reduce over this block's 128 rows) =====
    #pragma unroll
    for (int j = 0; j < 4; ++j) {
        float m = -3.4e38f;
        #pragma unroll
        for (int i = 0; i < 4; ++i)
            #pragma unroll
            for (int reg = 0; reg < 4; ++reg)
                m = fmaxf(m, acc[i][j][reg]);
        m = fmaxf(m, __shfl_xor(m, 16, 64));
        m = fmaxf(m, __shfl_xor(m, 32, 64));
        if (quad == 0) redB[(wc * 64 + j * 16 + ln15) * 2 + wr] = m;
    }
    __syncthreads();
    if (tid < 256) colMaxS[tid] = fmaxf(redB[tid * 2], redB[tid * 2 + 1]);
    __syncthreads();
    #pragma unroll
    for (int j = 0; j < 4; ++j) {
        int n = wc * 64 + j * 16 + ln15;
        float cm = colMaxS[n];
        float s = 0.f;
        #pragma unroll
        for (int i = 0; i < 4; ++i)
            #pragma unroll
            for (int reg = 0; reg < 4; ++reg)
                s += __expf(acc[i][j][reg] - cm);
        s += __shfl_xor(s, 16, 64);
        s += __shfl_xor(s, 32, 64);
        if (quad == 0) redB[n * 2 + wr] = s;
    }
    __syncthreads();
    if (tid < 256) {
        float s = redB[tid * 2] + redB[tid * 2 + 1];
        colM[(a * 256 + tid) * 2 + rt] = colMaxS[tid];
        colS[(a * 256 + tid) * 2 + rt] = s;
    }
}

// ---- block-wide reductions over 256 threads ----
__device__ __forceinline__ float blk_max(float v, float* sm) {
    #pragma unroll
    for (int d = 1; d < 64; d <<= 1) v = fmaxf(v, __shfl_xor(v, d, 64));
    __syncthreads();
    if ((threadIdx.x & 63) == 0) sm[threadIdx.x >> 6] = v;
    __syncthreads();
    return fmaxf(fmaxf(sm[0], sm[1]), fmaxf(sm[2], sm[3]));
}
__device__ __forceinline__ float blk_sum(float v, float* sm) {
    #pragma unroll
    for (int d = 1; d < 64; d <<= 1) v += __shfl_xor(v, d, 64);
    __syncthreads();
    if ((threadIdx.x & 63) == 0) sm[threadIdx.x >> 6] = v;
    __syncthreads();
    return sm[0] + sm[1] + sm[2] + sm[3];
}

// =====================================================================
// K3: per-index LSE combine + last-block final reduction
// =====================================================================
__global__ void combine_final(const float* __restrict__ rowM, const float* __restrict__ rowS,
                              const float* __restrict__ colM, const float* __restrict__ colS,
                              const float* __restrict__ diag,
                              float* __restrict__ m123, uint* __restrict__ counter,
                              float* __restrict__ out) {
    __shared__ float sm[4];
    __shared__ uint isLast;
    int b = blockIdx.x, t = threadIdx.x;
    float m = rowM[b * 256 + t], s = rowS[b * 256 + t];
    float M = blk_max(m, sm);
    float S = blk_sum(s * __expf(m - M), sm);
    float M1 = M + __logf(S);
    m = rowM[t * 256 + b]; s = rowS[t * 256 + b];
    M = blk_max(m, sm);
    S = blk_sum(s * __expf(m - M), sm);
    float M2 = M + __logf(S);
    float am = colM[(t * 256 + b) * 2 + 0], av = colS[(t * 256 + b) * 2 + 0];
    float bm = colM[(t * 256 + b) * 2 + 1], bv = colS[(t * 256 + b) * 2 + 1];
    m = fmaxf(am, bm);
    s = av * __expf(am - m) + bv * __expf(bm - m);
    M = blk_max(m, sm);
    S = blk_sum(s * __expf(m - M), sm);
    float M3 = M + __logf(S);
    if (t == 0) {
        m123[b] = M1 + M2 + M3;
        __threadfence();
        isLast = (atomicAdd(counter, 1u) == 255u) ? 1u : 0u;
    }
    __syncthreads();
    if (isLast) {
        __threadfence();
        const volatile float* vm = (const volatile float*)m123;
        const volatile float* vd = (const volatile float*)diag;
        float S1 = blk_sum(vm[t], sm);
        float S2 = blk_sum(vd[t], sm);
        if (t == 0) out[0] = S1 / 768.0f - S2 / 256.0f;
    }
}

extern "C" void kernel_launch(void* const* d_in, const int* in_sizes, int n_in,
                              void* d_out, int out_size, void* d_ws, size_t ws_size,
                              hipStream_t stream) {
    const float* x = (const float*)d_in[0];
    const float* y = (const float*)d_in[1];
    const float* z = (const float*)d_in[2];
    char* w = (char*)d_ws;
    ushort* zbf = (ushort*)(w);                  // 262144 B
    ushort* ybf = (ushort*)(w + 262144);         // 262144 B
    float* rowM = (float*)(w + 524288);          // 262144 B
    float* rowS = (float*)(w + 786432);          // 262144 B
    float* colM = (float*)(w + 1048576);         // 524288 B
    float* colS = (float*)(w + 1572864);         // 524288 B
    float* diag = (float*)(w + 2097152);         // 1024 B
    float* m123 = (float*)(w + 2098176);         // 1024 B
    uint*  counter = (uint*)(w + 2099200);       // 4 B
    float* out  = (float*)d_out;

    conv_swizzle<<<128, 256, 0, stream>>>(z, y, zbf, ybf);
    gemm_fused<<<512, 512, 0, stream>>>(x, y, z, ybf, zbf, rowM, rowS, colM, colS, diag, counter);
    combine_final<<<256, 256, 0, stream>>>(rowM, rowS, colM, colS, diag, m123, counter, out);
}